// Round 1
// baseline (219.139 us; speedup 1.0000x reference)
//
#include <hip/hip_runtime.h>

// CIF burst-mode neuron, closed form (elementwise, memory-bound).
// spike = (k_pos - k_neg) * th, with exact fp32 op-sequence matching the
// numpy/jax reference (no FMA contraction, IEEE-correct division) so that
// ceil/round integer boundaries land identically.

__device__ __forceinline__ float cif_one(float xv, float mv, float sv, float t) {
    // m = mem + x
    float m = __fadd_rn(mv, xv);
    // k_pos = max(ceil((m - t)/t), 0)
    float kpos = fmaxf(ceilf(__fdiv_rn(__fsub_rn(m, t), t)), 0.0f);
    // m1 = m - k_pos*t
    float kpt = __fmul_rn(kpos, t);
    float m1  = __fsub_rn(m, kpt);
    // sc_units = round((sc + k_pos*t)/t)   (round-half-even, like np.round)
    float sc_units = rintf(__fdiv_rn(__fadd_rn(sv, kpt), t));
    // j_mem = max(ceil((-m1 - t)/t), 0)
    float jmem = fmaxf(ceilf(__fdiv_rn(__fsub_rn(-m1, t), t)), 0.0f);
    // k_neg = min(j_mem, max(sc_units, 0))
    float kneg = fminf(jmem, fmaxf(sc_units, 0.0f));
    // spike = (k_pos - k_neg)*t
    return __fmul_rn(__fsub_rn(kpos, kneg), t);
}

__global__ __launch_bounds__(256) void CIFNeuron_36558761624015_kernel(
        const float4* __restrict__ x,
        const float4* __restrict__ mem,
        const float4* __restrict__ sc,
        const float*  __restrict__ th,
        float4* __restrict__ out,
        long long n4, int hmask /* H-1 */) {
    long long stride = (long long)gridDim.x * blockDim.x;
    for (long long i = (long long)blockIdx.x * blockDim.x + threadIdx.x;
         i < n4; i += stride) {
        float4 xv = x[i];
        float4 mv = mem[i];
        float4 sv = sc[i];
        // flat element index of lane 0 of this chunk; H divisible by 4 so the
        // 4 channels are a contiguous aligned float4 of threshold
        int h = (int)((i * 4) & (long long)hmask);
        float4 tv = *reinterpret_cast<const float4*>(th + h);
        float4 o;
        o.x = cif_one(xv.x, mv.x, sv.x, tv.x);
        o.y = cif_one(xv.y, mv.y, sv.y, tv.y);
        o.z = cif_one(xv.z, mv.z, sv.z, tv.z);
        o.w = cif_one(xv.w, mv.w, sv.w, tv.w);
        out[i] = o;
    }
}

extern "C" void kernel_launch(void* const* d_in, const int* in_sizes, int n_in,
                              void* d_out, int out_size, void* d_ws, size_t ws_size,
                              hipStream_t stream) {
    const float* x   = (const float*)d_in[0];
    const float* mem = (const float*)d_in[1];
    const float* sc  = (const float*)d_in[2];
    const float* th  = (const float*)d_in[3];
    float* out = (float*)d_out;

    const int H = in_sizes[3];            // 4096
    long long n  = (long long)out_size;   // B*T*H
    long long n4 = n / 4;

    int threads = 256;
    long long want = (n4 + threads - 1) / threads;
    int blocks = (int)((want < 2048) ? want : 2048);

    CIFNeuron_36558761624015_kernel<<<blocks, threads, 0, stream>>>(
        (const float4*)x, (const float4*)mem, (const float4*)sc, th,
        (float4*)out, n4, H - 1);
}

// Round 2
// 186.994 us; speedup vs baseline: 1.1719x; 1.1719x over previous
//
#include <hip/hip_runtime.h>

// CIF burst-mode neuron, closed form. Elementwise, memory/latency-bound.
// Exact fp32 op-sequence match on the two ceil-divides (boundary-sensitive);
// the round() divide is replaced by hw-rcp multiply (quotient is a small
// integer, error budget 0.5 absolute vs ~1e-5 actual).

typedef float v4f __attribute__((ext_vector_type(4)));

constexpr int TPB = 256;
constexpr int UF  = 4;   // float4-chunks per thread -> 12 global loads in flight

__device__ __forceinline__ float cif_one(float xv, float mv, float sv, float t) {
    // m = mem + x
    float m = __fadd_rn(mv, xv);
    // k_pos = max(ceil((m - t)/t), 0)   -- exact RN divide (boundary-sensitive)
    float kpos = fmaxf(ceilf(__fdiv_rn(__fsub_rn(m, t), t)), 0.0f);
    float kpt = __fmul_rn(kpos, t);
    float m1  = __fsub_rn(m, kpt);
    // sc_units = round((sc + k_pos*t)/t): quotient is integer counts+k_pos;
    // v_rcp_f32 (1 ulp) keeps error ~1e-5 << 0.5, so rintf is unaffected.
    float rt = __builtin_amdgcn_rcpf(t);
    float sc_units = rintf(__fmul_rn(__fadd_rn(sv, kpt), rt));
    // j_mem = max(ceil((-m1 - t)/t), 0)  -- exact RN divide
    float jmem = fmaxf(ceilf(__fdiv_rn(__fsub_rn(-m1, t), t)), 0.0f);
    float kneg = fminf(jmem, fmaxf(sc_units, 0.0f));
    return __fmul_rn(__fsub_rn(kpos, kneg), t);
}

__global__ __launch_bounds__(TPB) void CIFNeuron_36558761624015_kernel(
        const float4* __restrict__ x,
        const float4* __restrict__ mem,
        const float4* __restrict__ sc,
        const float*  __restrict__ th,
        float4* __restrict__ out,
        long long n4, int hmask /* H-1 */) {
    long long base = (long long)blockIdx.x * (TPB * UF) + threadIdx.x;

    float4 xv[UF], mv[UF], sv[UF], tv[UF];
    bool ok[UF];

    // Issue all global streaming loads first: 12 x 16B in flight per lane.
    #pragma unroll
    for (int k = 0; k < UF; ++k) {
        long long i = base + (long long)k * TPB;
        ok[k] = (i < n4);
        if (ok[k]) {
            xv[k] = x[i];
            mv[k] = mem[i];
            sv[k] = sc[i];
        }
    }
    // Threshold loads (16 KB table, L1/L2-resident).
    #pragma unroll
    for (int k = 0; k < UF; ++k) {
        if (ok[k]) {
            long long i = base + (long long)k * TPB;
            int h = (int)((i * 4) & (long long)hmask);
            tv[k] = *reinterpret_cast<const float4*>(th + h);
        }
    }
    // Compute + nontemporal store (don't let writes evict streamed inputs in L3).
    #pragma unroll
    for (int k = 0; k < UF; ++k) {
        if (ok[k]) {
            long long i = base + (long long)k * TPB;
            v4f o;
            o.x = cif_one(xv[k].x, mv[k].x, sv[k].x, tv[k].x);
            o.y = cif_one(xv[k].y, mv[k].y, sv[k].y, tv[k].y);
            o.z = cif_one(xv[k].z, mv[k].z, sv[k].z, tv[k].z);
            o.w = cif_one(xv[k].w, mv[k].w, sv[k].w, tv[k].w);
            __builtin_nontemporal_store(o, reinterpret_cast<v4f*>(out + i));
        }
    }
}

extern "C" void kernel_launch(void* const* d_in, const int* in_sizes, int n_in,
                              void* d_out, int out_size, void* d_ws, size_t ws_size,
                              hipStream_t stream) {
    const float* x   = (const float*)d_in[0];
    const float* mem = (const float*)d_in[1];
    const float* sc  = (const float*)d_in[2];
    const float* th  = (const float*)d_in[3];
    float* out = (float*)d_out;

    const int H = in_sizes[3];            // 4096
    long long n  = (long long)out_size;   // B*T*H, divisible by 4 (H%4==0)
    long long n4 = n / 4;

    long long per_block = (long long)TPB * UF;
    int blocks = (int)((n4 + per_block - 1) / per_block);

    CIFNeuron_36558761624015_kernel<<<blocks, TPB, 0, stream>>>(
        (const float4*)x, (const float4*)mem, (const float4*)sc, th,
        (float4*)out, n4, H - 1);
}